// Round 1
// baseline (362.616 us; speedup 1.0000x reference)
//
#include <hip/hip_runtime.h>
#include <math.h>

// B=8, N=256, D=128. score[b,i,j] = <val_i,val_j> + <dep_ij, dep_ji> is
// SYMMETRIC in (i,j) -> compute upper triangle only; each 512B dep row is
// fetched exactly once from HBM (256 MB floor). Memory-bound kernel.

#define BB 8
#define NN 256
#define DD 128

constexpr float EPS = 1e-10f;
constexpr float INV_SQRT_D = 0.08838834764831845f; // 1/sqrt(128)

constexpr int RECT_H = NN / 2;            // 128
constexpr int RECT_W = NN + 1;            // 257
constexpr int PAIRS_PER_BATCH = RECT_H * RECT_W;   // 32896 = N(N+1)/2
constexpr int TOTAL_PAIRS = BB * PAIRS_PER_BATCH;  // 263168
constexpr int PAIRS_PER_BLOCK = 8;                 // 256 threads / 32 lanes

__global__ __launch_bounds__(256) void score_kernel(
    const float* __restrict__ val,   // [B,N,D]
    const float* __restrict__ dep,   // [B,N,N,D]
    const float* __restrict__ adj,   // [B,N,N]
    float* __restrict__ out)         // [B,N,N] <- exp(score)*adj (unnormalized)
{
    const int pair = blockIdx.x * PAIRS_PER_BLOCK + (threadIdx.x >> 5);
    const int lane = threadIdx.x & 31;

    const int b = pair / PAIRS_PER_BATCH;
    const int t = pair - b * PAIRS_PER_BATCH;
    const int r = t / RECT_W;
    const int c = t - r * RECT_W;
    // triangle<->rectangle: row r pairs with row N-1-r
    int i, j;
    if (c < NN - r) { i = r;          j = r + c; }
    else            { i = NN - 1 - r; j = c - 1; }

    const float4* dij = (const float4*)(dep + (((size_t)b * NN + i) * NN + j) * DD);
    const float4* dji = (const float4*)(dep + (((size_t)b * NN + j) * NN + i) * DD);
    const float4* vi  = (const float4*)(val + ((size_t)b * NN + i) * DD);
    const float4* vj  = (const float4*)(val + ((size_t)b * NN + j) * DD);

    const float4 a  = dij[lane];
    const float4 bt = dji[lane];
    const float4 x  = vi[lane];
    const float4 y  = vj[lane];

    float p = a.x * bt.x + a.y * bt.y + a.z * bt.z + a.w * bt.w
            + x.x * y.x  + x.y * y.y  + x.z * y.z  + x.w * y.w;

    // reduce across the 32-lane half-wave (xor masks 1..16 stay within halves)
    #pragma unroll
    for (int m = 16; m >= 1; m >>= 1) p += __shfl_xor(p, m, 64);

    if (lane == 0) {
        const float e = __expf(p * INV_SQRT_D);
        const size_t base = (size_t)b * NN * NN;
        const size_t ij = base + (size_t)i * NN + j;
        const size_t ji = base + (size_t)j * NN + i;
        out[ij] = e * adj[ij];
        out[ji] = e * adj[ji];   // i==j: same addr, same value, same thread -> fine
    }
}

__global__ __launch_bounds__(256) void norm_kernel(float* __restrict__ out)
{
    const int row = blockIdx.x;              // b*N + i
    const int tid = threadIdx.x;             // j
    const size_t idx = (size_t)row * NN + tid;
    const float x = out[idx];

    // wave64 reduce
    float s = x;
    #pragma unroll
    for (int m = 32; m >= 1; m >>= 1) s += __shfl_xor(s, m, 64);

    __shared__ float ws[4];
    __shared__ float denom_s;
    const int wid = tid >> 6;
    if ((tid & 63) == 0) ws[wid] = s;
    __syncthreads();
    if (tid == 0) denom_s = ws[0] + ws[1] + ws[2] + ws[3] + EPS;
    __syncthreads();

    out[idx] = x / denom_s;
}

extern "C" void kernel_launch(void* const* d_in, const int* in_sizes, int n_in,
                              void* d_out, int out_size, void* d_ws, size_t ws_size,
                              hipStream_t stream) {
    const float* val = (const float*)d_in[0];
    const float* dep = (const float*)d_in[1];
    const float* adj = (const float*)d_in[2];
    float* out = (float*)d_out;

    static_assert(TOTAL_PAIRS % PAIRS_PER_BLOCK == 0, "grid exact");
    score_kernel<<<TOTAL_PAIRS / PAIRS_PER_BLOCK, 256, 0, stream>>>(val, dep, adj, out);
    norm_kernel<<<BB * NN, 256, 0, stream>>>(out);
}